// Round 1
// baseline (1478.796 us; speedup 1.0000x reference)
//
#include <hip/hip_runtime.h>
#include <hip/hip_bf16.h>

#define NW 256   // WIDTH
#define NDEPTH 10

// ---------------- forward fc: out = relu(in @ W.T + bias) [+ res] ----------------
__global__ void fc_kernel(const float* __restrict__ in, const float* __restrict__ W,
                          const float* __restrict__ bias, const float* __restrict__ res,
                          float* __restrict__ out, int K, int do_relu) {
  const int b = blockIdx.x;   // batch row
  const int o = threadIdx.x;  // output unit (256)
  const float* inr = in + (size_t)b * K;
  const float* wr  = W + (size_t)o * K;
  float s = bias[o];
  for (int k = 0; k < K; k += 4) {
    float4 x = *(const float4*)(inr + k);
    float4 w = *(const float4*)(wr + k);
    s += x.x * w.x + x.y * w.y + x.z * w.z + x.w * w.w;
  }
  if (do_relu) s = fmaxf(s, 0.f);
  if (res) s += res[(size_t)b * NW + o];
  out[(size_t)b * NW + o] = s;
}

__global__ void lastfc_kernel(const float* __restrict__ y, const float* __restrict__ Wl,
                              const float* __restrict__ bl, float* __restrict__ out) {
  const int o = blockIdx.x;   // 10
  const int b = threadIdx.x;  // 256
  const float* yr = y + b * NW;
  const float* wr = Wl + o * NW;
  float s = 0.f;
  for (int k = 0; k < NW; k += 4) {
    float4 x = *(const float4*)(yr + k);
    float4 w = *(const float4*)(wr + k);
    s += x.x * w.x + x.y * w.y + x.z * w.z + x.w * w.w;
  }
  out[b * 10 + o] = s + bl[o];
}

// ---------------- B = (I+W)^T (I+W) for all 10 blocks ----------------
// B[r][c] = sum_j W[j][r]*W[j][c] + W[c][r] + W[r][c] + (r==c)
__global__ void bmat_kernel(const float* __restrict__ Wb, float* __restrict__ Ball) {
  const int blk = blockIdx.x;        // 10 * 32
  const int k   = blk >> 5;
  const int r0  = (blk & 31) << 3;   // 8 rows per block
  const int c   = threadIdx.x;       // 256
  const float* W = Wb + (size_t)k * NW * NW;
  float acc[8] = {0.f,0.f,0.f,0.f,0.f,0.f,0.f,0.f};
  for (int j = 0; j < NW; ++j) {
    const float wc = W[j * NW + c];
#pragma unroll
    for (int rr = 0; rr < 8; ++rr) acc[rr] += wc * W[j * NW + r0 + rr];
  }
#pragma unroll
  for (int rr = 0; rr < 8; ++rr) {
    const int r = r0 + rr;
    float s = acc[rr] + W[c * NW + r] + W[r * NW + c] + ((r == c) ? 1.f : 0.f);
    Ball[(size_t)k * NW * NW + r * NW + c] = s;
  }
}

// ---------------- eigen kernel: Householder tridiag (B in regs) + Sturm bisection ----------------
__global__ __launch_bounds__(1024, 1) void eig_kernel(const float* __restrict__ Ball,
                                                      float* __restrict__ sig) {
  const int blk = blockIdx.x;      // 0..9
  const int t = threadIdx.x;       // 0..1023
  const int r = t & 255;           // owned row
  const int q = t >> 8;            // column chunk 0..3
  const int c0 = q << 6;           // chunk base column

  __shared__ __align__(16) float vcol[NW];
  __shared__ __align__(16) float vv[NW];
  __shared__ __align__(16) float ww[NW];
  __shared__ __align__(16) float w4[4][NW];
  __shared__ float red[8];
  __shared__ float dd[NW];
  __shared__ float ee2[NW];

  // load my 64 entries of B
  float Bv[64];
  {
    const float* src = Ball + (size_t)blk * NW * NW + (size_t)r * NW + c0;
#pragma unroll
    for (int i = 0; i < 16; ++i) {
      const float4 f = *(const float4*)(src + 4 * i);
      Bv[4*i+0] = f.x; Bv[4*i+1] = f.y; Bv[4*i+2] = f.z; Bv[4*i+3] = f.w;
    }
  }

  // initial dump of row 0 + sumsq over c>0
  if (r == 0) {
    float s = 0.f;
#pragma unroll
    for (int j = 0; j < 64; ++j) {
      vcol[c0 + j] = Bv[j];
      if (c0 + j > 0) s += Bv[j] * Bv[j];
    }
    red[q] = s;
  }
  __syncthreads();

  for (int i = 0; i < NW - 2; ++i) {
    // ---- scalars + build v (threads <256) ----
    float tau = 0.f;
    if (t < NW) {
      const float norm2 = red[0] + red[1] + red[2] + red[3];
      const float head  = vcol[i + 1];
      const float alpha = -copysignf(sqrtf(norm2), head);
      const float v1    = head - alpha;
      const float vn2   = norm2 - head * head + v1 * v1;
      tau = (vn2 > 1e-32f) ? 2.f / vn2 : 0.f;
      if (t == 0) { dd[i] = vcol[i]; ee2[i] = norm2; }
      vv[t] = (t <= i) ? 0.f : ((t == i + 1) ? v1 : vcol[t]);
    }
    __syncthreads();

    // ---- matvec partials: w4[q][r] = sum_j B[r][c0+j] * v[c0+j] ----
    {
      float s = 0.f;
      if (r > i && (c0 + 63) > i) {
#pragma unroll
        for (int j = 0; j < 64; j += 4) {
          const float4 vx = *(const float4*)&vv[c0 + j];
          s += Bv[j] * vx.x + Bv[j+1] * vx.y + Bv[j+2] * vx.z + Bv[j+3] * vx.w;
        }
      }
      w4[q][r] = s;
    }
    __syncthreads();

    // ---- p = tau*B*v; reduce v.p ----
    if (t < NW) {
      const float p = (t > i) ? tau * (w4[0][t] + w4[1][t] + w4[2][t] + w4[3][t]) : 0.f;
      ww[t] = p;
      float s = vv[t] * p;
#pragma unroll
      for (int off = 32; off; off >>= 1) s += __shfl_down(s, off);
      if ((t & 63) == 0) red[4 + (t >> 6)] = s;
    }
    __syncthreads();

    // ---- w = p - (tau*(v.p)/2) v ----
    if (t < NW) {
      const float vp = red[4] + red[5] + red[6] + red[7];
      const float Kc = 0.5f * tau * vp;
      ww[t] -= Kc * vv[t];
    }
    __syncthreads();

    // ---- rank-2 update (trailing block) + dump row i+1 for next step ----
    if (r > i && (c0 + 63) > i) {
      const float vr = vv[r], wr_ = ww[r];
#pragma unroll
      for (int j = 0; j < 64; j += 4) {
        const float4 vx = *(const float4*)&vv[c0 + j];
        const float4 wx = *(const float4*)&ww[c0 + j];
        Bv[j+0] -= vr * wx.x + wr_ * vx.x;
        Bv[j+1] -= vr * wx.y + wr_ * vx.y;
        Bv[j+2] -= vr * wx.z + wr_ * vx.z;
        Bv[j+3] -= vr * wx.w + wr_ * vx.w;
      }
    }
    if (r == i + 1) {
      float s = 0.f;
#pragma unroll
      for (int j = 0; j < 64; ++j) {
        vcol[c0 + j] = Bv[j];
        if (c0 + j > i + 1) s += Bv[j] * Bv[j];
      }
      red[q] = s;
    }
    __syncthreads();
  }

  // epilogue: vcol = row 254, red = sumsq over c>254
  if (t == 0) {
    dd[254] = vcol[254];
    ee2[254] = red[0] + red[1] + red[2] + red[3];
    ee2[255] = 0.f;
  }
  if (r == 255 && q == 3) dd[255] = Bv[63];  // B[255][255]
  __syncthreads();

  // Gershgorin bounds
  if (t < NW) {
    const float ej  = (t < 255) ? sqrtf(ee2[t]) : 0.f;
    const float ejm = (t > 0) ? sqrtf(ee2[t - 1]) : 0.f;
    float lo = dd[t] - (ej + ejm);
    float hi = dd[t] + (ej + ejm);
#pragma unroll
    for (int off = 32; off; off >>= 1) {
      lo = fminf(lo, __shfl_down(lo, off));
      hi = fmaxf(hi, __shfl_down(hi, off));
    }
    if ((t & 63) == 0) { red[t >> 6] = lo; red[4 + (t >> 6)] = hi; }
  }
  __syncthreads();

  // bisection: thread t finds t-th smallest eigenvalue
  if (t < NW) {
    float lo = fminf(fminf(red[0], red[1]), fminf(red[2], red[3]));
    float hi = fmaxf(fmaxf(red[4], red[5]), fmaxf(red[6], red[7]));
    lo = fminf(lo, 0.f);  // B is PSD
    const int target = t;
    for (int it = 0; it < 30; ++it) {
      const float mid = 0.5f * (lo + hi);
      int cnt = 0;
      float qv = dd[0] - mid;
      cnt += (qv < 0.f);
      for (int j = 1; j < NW; ++j) {
        float denom = (fabsf(qv) < 1e-20f) ? -1e-20f : qv;
        qv = dd[j] - mid - ee2[j - 1] * __builtin_amdgcn_rcpf(denom);
        cnt += (qv < 0.f);
      }
      if (cnt > target) hi = mid; else lo = mid;
    }
    const float lam = 0.5f * (lo + hi);
    sig[blk * NW + (255 - t)] = sqrtf(fmaxf(lam, 0.f));  // descending
  }
}

// ---------------- mean over blocks, broadcast over batch ----------------
__global__ void sig_avg_kernel(const float* __restrict__ sig, float* __restrict__ out_all) {
  const int b = blockIdx.x;   // 256
  const int j = threadIdx.x;  // 256
  float s = 0.f;
#pragma unroll
  for (int k = 0; k < NDEPTH; ++k) s += sig[k * NW + j];
  out_all[b * NW + j] = s * 0.1f;
}

extern "C" void kernel_launch(void* const* d_in, const int* in_sizes, int n_in,
                              void* d_out, int out_size, void* d_ws, size_t ws_size,
                              hipStream_t stream) {
  const float* x  = (const float*)d_in[0];  // [256,784]
  const float* W1 = (const float*)d_in[1];  // [256,784]
  const float* b1 = (const float*)d_in[2];  // [256]
  const float* Wb = (const float*)d_in[3];  // [10,256,256]
  const float* bb = (const float*)d_in[4];  // [10,256]
  const float* Wl = (const float*)d_in[5];  // [10,256]
  const float* bl = (const float*)d_in[6];  // [10]
  float* out = (float*)d_out;               // 2560 + 65536

  float* ws = (float*)d_ws;
  float* y0   = ws;                 // 65536
  float* y1   = ws + 65536;         // 65536
  float* Ball = ws + 131072;        // 10*65536
  float* sigw = ws + 786432;        // 10*256

  // eigen path (the long pole)
  bmat_kernel<<<dim3(NDEPTH * 32), dim3(256), 0, stream>>>(Wb, Ball);
  eig_kernel<<<dim3(NDEPTH), dim3(1024), 0, stream>>>(Ball, sigw);

  // forward path
  fc_kernel<<<dim3(256), dim3(256), 0, stream>>>(x, W1, b1, nullptr, y0, 784, 1);
  float* cur = y0;
  float* nxt = y1;
  for (int d = 0; d < NDEPTH; ++d) {
    fc_kernel<<<dim3(256), dim3(256), 0, stream>>>(cur, Wb + (size_t)d * 65536,
                                                   bb + d * 256, cur, nxt, 256, 1);
    float* tmp = cur; cur = nxt; nxt = tmp;
  }
  lastfc_kernel<<<dim3(10), dim3(256), 0, stream>>>(cur, Wl, bl, out);

  // all_sigma output
  sig_avg_kernel<<<dim3(256), dim3(256), 0, stream>>>(sigw, out + 2560);
}